// Round 1
// baseline (1077.581 us; speedup 1.0000x reference)
//
#include <hip/hip_runtime.h>
#include <hip/hip_bf16.h>
#include <cstdint>
#include <cstddef>

// Problem constants (MSA row attention, openfold-style)
#define S_  128
#define R_  384
#define C_  256
#define H_  8
#define D_  32
#define HD_ 256          // H*D
#define M_  (S_*R_)      // 49152 rows total

// ---------------------------------------------------------------------------
// Kernel 1: LayerNorm over C=256. One wave (64 lanes) per row, float4/lane.
// ---------------------------------------------------------------------------
__global__ __launch_bounds__(256) void ln_kernel(const float* __restrict__ mIn,
                                                 const float* __restrict__ w,
                                                 const float* __restrict__ b,
                                                 float* __restrict__ x) {
  int row  = blockIdx.x * 4 + (threadIdx.x >> 6);
  int lane = threadIdx.x & 63;
  const float4 v4 = *(const float4*)(mIn + (size_t)row * C_ + lane * 4);
  float s  = v4.x + v4.y + v4.z + v4.w;
  float ss = v4.x*v4.x + v4.y*v4.y + v4.z*v4.z + v4.w*v4.w;
#pragma unroll
  for (int off = 32; off > 0; off >>= 1) {
    s  += __shfl_xor(s,  off);
    ss += __shfl_xor(ss, off);
  }
  float mu  = s * (1.0f / C_);
  float var = ss * (1.0f / C_) - mu * mu;
  float rs  = rsqrtf(var + 1e-5f);
  const float4 wv = *(const float4*)(w + lane * 4);
  const float4 bv = *(const float4*)(b + lane * 4);
  float4 o;
  o.x = (v4.x - mu) * rs * wv.x + bv.x;
  o.y = (v4.y - mu) * rs * wv.y + bv.y;
  o.z = (v4.z - mu) * rs * wv.z + bv.z;
  o.w = (v4.w - mu) * rs * wv.w + bv.w;
  *(float4*)(x + (size_t)row * C_ + lane * 4) = o;
}

// ---------------------------------------------------------------------------
// Kernel 2: fused QKVG projection. X[M,256] @ {wq,wk,wv,wg}[256,256].
// Tiled fp32 GEMM: BM=BN=64, BK=16, 256 threads, 4x4 outputs/thread.
// Epilogue: q *= D^-0.5 ; g = sigmoid(g + bg).
// ---------------------------------------------------------------------------
#define BM 64
#define BN 64
#define BK 16

__global__ __launch_bounds__(256) void proj_gemm(const float* __restrict__ X,
    const float* __restrict__ wq, const float* __restrict__ wk,
    const float* __restrict__ wv, const float* __restrict__ wg,
    const float* __restrict__ bg,
    float* __restrict__ Q, float* __restrict__ K,
    float* __restrict__ V, float* __restrict__ G) {
  __shared__ float As[BK][BM + 4];   // +4 pad: stride 68 floats, 16B-aligned rows
  __shared__ float Bs[BK][BN];

  const int bm   = blockIdx.x * BM;
  const int wsel = blockIdx.y >> 2;          // which weight (4 n-tiles each)
  const int bn   = (blockIdx.y & 3) * BN;    // col offset within that weight
  const float* W = (wsel == 0) ? wq : (wsel == 1) ? wk : (wsel == 2) ? wv : wg;
  float*       O = (wsel == 0) ? Q  : (wsel == 1) ? K  : (wsel == 2) ? V  : G;

  const int tid = threadIdx.x;
  const int tx  = tid & 15;   // n group: cols bn + tx*4 .. +3
  const int ty  = tid >> 4;   // m group: rows bm + ty*4 .. +3

  float4 acc[4];
#pragma unroll
  for (int i = 0; i < 4; i++) acc[i] = make_float4(0.f, 0.f, 0.f, 0.f);

  for (int k0 = 0; k0 < C_; k0 += BK) {
    {   // A tile 64x16 (transposed into LDS)
      int r = tid >> 2, c = (tid & 3) << 2;
      float4 a4 = *(const float4*)(X + (size_t)(bm + r) * C_ + k0 + c);
      As[c + 0][r] = a4.x; As[c + 1][r] = a4.y;
      As[c + 2][r] = a4.z; As[c + 3][r] = a4.w;
    }
    {   // B tile 16x64
      int r = tid >> 4, c = (tid & 15) << 2;
      *(float4*)(&Bs[r][c]) = *(const float4*)(W + (size_t)(k0 + r) * HD_ + bn + c);
    }
    __syncthreads();
#pragma unroll
    for (int kk = 0; kk < BK; kk++) {
      float4 av = *(const float4*)(&As[kk][ty << 2]);
      float4 bv = *(const float4*)(&Bs[kk][tx << 2]);
      acc[0].x = fmaf(av.x, bv.x, acc[0].x); acc[0].y = fmaf(av.x, bv.y, acc[0].y);
      acc[0].z = fmaf(av.x, bv.z, acc[0].z); acc[0].w = fmaf(av.x, bv.w, acc[0].w);
      acc[1].x = fmaf(av.y, bv.x, acc[1].x); acc[1].y = fmaf(av.y, bv.y, acc[1].y);
      acc[1].z = fmaf(av.y, bv.z, acc[1].z); acc[1].w = fmaf(av.y, bv.w, acc[1].w);
      acc[2].x = fmaf(av.z, bv.x, acc[2].x); acc[2].y = fmaf(av.z, bv.y, acc[2].y);
      acc[2].z = fmaf(av.z, bv.z, acc[2].z); acc[2].w = fmaf(av.z, bv.w, acc[2].w);
      acc[3].x = fmaf(av.w, bv.x, acc[3].x); acc[3].y = fmaf(av.w, bv.y, acc[3].y);
      acc[3].z = fmaf(av.w, bv.z, acc[3].z); acc[3].w = fmaf(av.w, bv.w, acc[3].w);
    }
    __syncthreads();
  }

  const float qscale = 0.17677669529663687f;   // 32^-0.5
  float4 bgv = make_float4(0.f, 0.f, 0.f, 0.f);
  if (wsel == 3) bgv = *(const float4*)(bg + bn + (tx << 2));
#pragma unroll
  for (int i = 0; i < 4; i++) {
    float4 o4 = acc[i];
    if (wsel == 0) {
      o4.x *= qscale; o4.y *= qscale; o4.z *= qscale; o4.w *= qscale;
    } else if (wsel == 3) {
      o4.x = 1.0f / (1.0f + __expf(-(o4.x + bgv.x)));
      o4.y = 1.0f / (1.0f + __expf(-(o4.y + bgv.y)));
      o4.z = 1.0f / (1.0f + __expf(-(o4.z + bgv.z)));
      o4.w = 1.0f / (1.0f + __expf(-(o4.w + bgv.w)));
    }
    int row = bm + (ty << 2) + i;
    *(float4*)(O + (size_t)row * HD_ + bn + (tx << 2)) = o4;
  }
}

// ---------------------------------------------------------------------------
// Kernel 3: flash-style attention per (s,h), thread-per-q-row, online softmax.
// K/V tiles of 128 rows staged in LDS; broadcast float4 reads in inner loop.
// Epilogue fuses the sigmoid gate and writes gated o back to the xn buffer.
// ---------------------------------------------------------------------------
#define KT_ 128

__global__ __launch_bounds__(128) void attn_kernel(const float* __restrict__ q,
    const float* __restrict__ k, const float* __restrict__ v,
    const float* __restrict__ g, const float* __restrict__ mask,
    float* __restrict__ o) {
  __shared__ float ks[KT_][D_];
  __shared__ float vs[KT_][D_];
  __shared__ float mb[KT_];

  const int tid  = threadIdx.x;
  const int qrow = blockIdx.x * 128 + tid;
  const int h    = blockIdx.y;
  const int s    = blockIdx.z;
  const size_t qoff = (size_t)(s * R_ + qrow) * HD_ + h * D_;

  float4 qv[8];
#pragma unroll
  for (int i = 0; i < 8; i++) qv[i] = *(const float4*)(q + qoff + i * 4);
  float4 oa[8];
#pragma unroll
  for (int i = 0; i < 8; i++) oa[i] = make_float4(0.f, 0.f, 0.f, 0.f);

  float mrun = -1e30f, lrun = 0.0f;

  for (int kt = 0; kt < R_; kt += KT_) {
    __syncthreads();
#pragma unroll
    for (int i = 0; i < 8; i++) {      // stage K/V tile: 128x32 floats each
      int idx = i * 128 + tid;
      int r = idx >> 3, c = (idx & 7) << 2;
      size_t goff = (size_t)(s * R_ + kt + r) * HD_ + h * D_ + c;
      *(float4*)(&ks[r][c]) = *(const float4*)(k + goff);
      *(float4*)(&vs[r][c]) = *(const float4*)(v + goff);
    }
    mb[tid] = 1e9f * (mask[s * R_ + kt + tid] - 1.0f);
    __syncthreads();

    for (int j = 0; j < KT_; j++) {
      float dot = 0.f;
#pragma unroll
      for (int dd = 0; dd < 8; dd++) {
        float4 kv = *(const float4*)(&ks[j][dd << 2]);
        dot = fmaf(qv[dd].x, kv.x, dot);
        dot = fmaf(qv[dd].y, kv.y, dot);
        dot = fmaf(qv[dd].z, kv.z, dot);
        dot = fmaf(qv[dd].w, kv.w, dot);
      }
      float sc = dot + mb[j];
      if (sc <= mrun) {                 // common path: no new max, no rescale
        float p = __expf(sc - mrun);
        lrun += p;
#pragma unroll
        for (int dd = 0; dd < 8; dd++) {
          float4 vv = *(const float4*)(&vs[j][dd << 2]);
          oa[dd].x = fmaf(p, vv.x, oa[dd].x);
          oa[dd].y = fmaf(p, vv.y, oa[dd].y);
          oa[dd].z = fmaf(p, vv.z, oa[dd].z);
          oa[dd].w = fmaf(p, vv.w, oa[dd].w);
        }
      } else {                          // new max: rescale old state, p == 1
        float sc2 = __expf(mrun - sc);  // exp(-1e30-...) -> 0 on first hit
        lrun = fmaf(lrun, sc2, 1.0f);
        mrun = sc;
#pragma unroll
        for (int dd = 0; dd < 8; dd++) {
          float4 vv = *(const float4*)(&vs[j][dd << 2]);
          oa[dd].x = fmaf(oa[dd].x, sc2, vv.x);
          oa[dd].y = fmaf(oa[dd].y, sc2, vv.y);
          oa[dd].z = fmaf(oa[dd].z, sc2, vv.z);
          oa[dd].w = fmaf(oa[dd].w, sc2, vv.w);
        }
      }
    }
  }

  const float inv = 1.0f / lrun;
#pragma unroll
  for (int i = 0; i < 8; i++) {        // fuse gate, write gated o
    float4 gv = *(const float4*)(g + qoff + i * 4);
    float4 ov;
    ov.x = oa[i].x * inv * gv.x;
    ov.y = oa[i].y * inv * gv.y;
    ov.z = oa[i].z * inv * gv.z;
    ov.w = oa[i].w * inv * gv.w;
    *(float4*)(o + qoff + i * 4) = ov;
  }
}

// ---------------------------------------------------------------------------
// Kernel 4: output GEMM. A[M,256] @ wo[256,256] + bo -> out.
// ---------------------------------------------------------------------------
__global__ __launch_bounds__(256) void out_gemm(const float* __restrict__ A,
    const float* __restrict__ W, const float* __restrict__ bo,
    float* __restrict__ Out) {
  __shared__ float As[BK][BM + 4];
  __shared__ float Bs[BK][BN];

  const int bm = blockIdx.x * BM;
  const int bn = blockIdx.y * BN;
  const int tid = threadIdx.x;
  const int tx = tid & 15;
  const int ty = tid >> 4;

  float4 acc[4];
#pragma unroll
  for (int i = 0; i < 4; i++) acc[i] = make_float4(0.f, 0.f, 0.f, 0.f);

  for (int k0 = 0; k0 < HD_; k0 += BK) {
    {
      int r = tid >> 2, c = (tid & 3) << 2;
      float4 a4 = *(const float4*)(A + (size_t)(bm + r) * HD_ + k0 + c);
      As[c + 0][r] = a4.x; As[c + 1][r] = a4.y;
      As[c + 2][r] = a4.z; As[c + 3][r] = a4.w;
    }
    {
      int r = tid >> 4, c = (tid & 15) << 2;
      *(float4*)(&Bs[r][c]) = *(const float4*)(W + (size_t)(k0 + r) * C_ + bn + c);
    }
    __syncthreads();
#pragma unroll
    for (int kk = 0; kk < BK; kk++) {
      float4 av = *(const float4*)(&As[kk][ty << 2]);
      float4 bv = *(const float4*)(&Bs[kk][tx << 2]);
      acc[0].x = fmaf(av.x, bv.x, acc[0].x); acc[0].y = fmaf(av.x, bv.y, acc[0].y);
      acc[0].z = fmaf(av.x, bv.z, acc[0].z); acc[0].w = fmaf(av.x, bv.w, acc[0].w);
      acc[1].x = fmaf(av.y, bv.x, acc[1].x); acc[1].y = fmaf(av.y, bv.y, acc[1].y);
      acc[1].z = fmaf(av.y, bv.z, acc[1].z); acc[1].w = fmaf(av.y, bv.w, acc[1].w);
      acc[2].x = fmaf(av.z, bv.x, acc[2].x); acc[2].y = fmaf(av.z, bv.y, acc[2].y);
      acc[2].z = fmaf(av.z, bv.z, acc[2].z); acc[2].w = fmaf(av.z, bv.w, acc[2].w);
      acc[3].x = fmaf(av.w, bv.x, acc[3].x); acc[3].y = fmaf(av.w, bv.y, acc[3].y);
      acc[3].z = fmaf(av.w, bv.z, acc[3].z); acc[3].w = fmaf(av.w, bv.w, acc[3].w);
    }
    __syncthreads();
  }

  float4 bv = *(const float4*)(bo + bn + (tx << 2));
#pragma unroll
  for (int i = 0; i < 4; i++) {
    float4 o4;
    o4.x = acc[i].x + bv.x; o4.y = acc[i].y + bv.y;
    o4.z = acc[i].z + bv.z; o4.w = acc[i].w + bv.w;
    int row = bm + (ty << 2) + i;
    *(float4*)(Out + (size_t)row * C_ + bn + (tx << 2)) = o4;
  }
}

// ---------------------------------------------------------------------------
// Host launcher
// ---------------------------------------------------------------------------
extern "C" void kernel_launch(void* const* d_in, const int* in_sizes, int n_in,
                              void* d_out, int out_size, void* d_ws, size_t ws_size,
                              hipStream_t stream) {
  const float* m    = (const float*)d_in[0];
  const float* mask = (const float*)d_in[1];
  const float* ln_w = (const float*)d_in[2];
  const float* ln_b = (const float*)d_in[3];
  const float* wq   = (const float*)d_in[4];
  const float* wk   = (const float*)d_in[5];
  const float* wv   = (const float*)d_in[6];
  const float* wg   = (const float*)d_in[7];
  const float* bg   = (const float*)d_in[8];
  const float* wo   = (const float*)d_in[9];
  const float* bo   = (const float*)d_in[10];
  float* out = (float*)d_out;

  // Workspace layout (floats): xn | q | k | v | g  — 5 * 12.58M floats = 252 MB.
  // Attention writes its gated output over xn (xn dead after projections).
  float* ws  = (float*)d_ws;
  const size_t SZ = (size_t)M_ * C_;
  float* xn = ws;
  float* qb = ws + 1 * SZ;
  float* kb = ws + 2 * SZ;
  float* vb = ws + 3 * SZ;
  float* gb = ws + 4 * SZ;

  ln_kernel<<<M_ / 4, 256, 0, stream>>>(m, ln_w, ln_b, xn);
  proj_gemm<<<dim3(M_ / BM, 16), 256, 0, stream>>>(xn, wq, wk, wv, wg, bg,
                                                   qb, kb, vb, gb);
  attn_kernel<<<dim3(R_ / KT_, H_, S_), KT_, 0, stream>>>(qb, kb, vb, gb, mask, xn);
  out_gemm<<<dim3(M_ / BM, C_ / BN), 256, 0, stream>>>(xn, wo, bo, out);
}

// Round 2
// 270.533 us; speedup vs baseline: 3.9832x; 3.9832x over previous
//
#include <hip/hip_runtime.h>
#include <cstdint>
#include <cstddef>

// MSA row attention (openfold-style), bf16 MFMA pipeline.
#define S_  128
#define R_  384
#define C_  256
#define H_  8
#define D_  32
#define HD_ 256
#define M_  (S_*R_)      // 49152

typedef float f32x16 __attribute__((ext_vector_type(16)));
typedef short s16x8  __attribute__((ext_vector_type(8)));
typedef int   i32x4  __attribute__((ext_vector_type(4)));

// bf16 helpers (RNE), buffers held as ushort to avoid hip_bf16 API churn.
__device__ __forceinline__ unsigned short f2bf(float f) {
  uint32_t u = __float_as_uint(f);
  u += 0x7fffu + ((u >> 16) & 1u);
  return (unsigned short)(u >> 16);
}
__device__ __forceinline__ float bf2f(unsigned short s) {
  return __uint_as_float(((uint32_t)s) << 16);
}
__device__ __forceinline__ uint32_t pkbf(float lo, float hi) {
  return (uint32_t)f2bf(lo) | ((uint32_t)f2bf(hi) << 16);
}
#define MFMA32(a,b,c) __builtin_amdgcn_mfma_f32_32x32x16_bf16((a),(b),(c),0,0,0)

// ---------------------------------------------------------------------------
// Kernel 0: weight prep — transpose + cvt to bf16. WT[mat][n][k] = W[mat][k][n].
// mats: 0..3 = wq,wk,wv,wg ([C][HD]); 4 = wo ([HD][C]).
// ---------------------------------------------------------------------------
__global__ __launch_bounds__(256) void prep_w(const float* __restrict__ wq,
    const float* __restrict__ wk, const float* __restrict__ wv,
    const float* __restrict__ wg, const float* __restrict__ wo,
    unsigned short* __restrict__ WT) {
  int idx = blockIdx.x * 256 + threadIdx.x;   // 5*65536
  int mat = idx >> 16;
  int rem = idx & 65535;
  int n = rem >> 8, k = rem & 255;
  const float* W = (mat==0)?wq:(mat==1)?wk:(mat==2)?wv:(mat==3)?wg:wo;
  WT[idx] = f2bf(W[k*256 + n]);
}

// ---------------------------------------------------------------------------
// Kernel 1: LayerNorm over C=256, one wave per row, writes bf16.
// ---------------------------------------------------------------------------
__global__ __launch_bounds__(256) void ln_kernel(const float* __restrict__ mIn,
    const float* __restrict__ w, const float* __restrict__ b,
    unsigned short* __restrict__ x) {
  int row  = blockIdx.x * 4 + (threadIdx.x >> 6);
  int lane = threadIdx.x & 63;
  const float4 v4 = *(const float4*)(mIn + (size_t)row * C_ + lane * 4);
  float s  = v4.x + v4.y + v4.z + v4.w;
  float ss = v4.x*v4.x + v4.y*v4.y + v4.z*v4.z + v4.w*v4.w;
#pragma unroll
  for (int off = 32; off > 0; off >>= 1) {
    s  += __shfl_xor(s,  off);
    ss += __shfl_xor(ss, off);
  }
  float mu  = s * (1.0f / C_);
  float var = ss * (1.0f / C_) - mu * mu;
  float rs  = rsqrtf(var + 1e-5f);
  const float4 wv = *(const float4*)(w + lane * 4);
  const float4 bv = *(const float4*)(b + lane * 4);
  uint2 o2;
  o2.x = pkbf((v4.x - mu) * rs * wv.x + bv.x, (v4.y - mu) * rs * wv.y + bv.y);
  o2.y = pkbf((v4.z - mu) * rs * wv.z + bv.z, (v4.w - mu) * rs * wv.w + bv.w);
  *(uint2*)(x + (size_t)row * C_ + lane * 4) = o2;
}

// ---------------------------------------------------------------------------
// Kernel 2: fused QKVG projection, bf16 MFMA. 128x128 tile, BK=32, 4 waves 2x2.
// A-frag: lane holds A[lane&31][8*(lane>>5)+j] (contiguous 8) -> ds_read_b128.
// Epilogue: Q *= D^-0.5 ; G = sigmoid(G + bg). Outputs bf16 [M][256].
// ---------------------------------------------------------------------------
__global__ __launch_bounds__(256) void proj_gemm(const unsigned short* __restrict__ X,
    const unsigned short* __restrict__ WT, const float* __restrict__ bg,
    unsigned short* __restrict__ Qo, unsigned short* __restrict__ Ko,
    unsigned short* __restrict__ Vo, unsigned short* __restrict__ Go) {
  __shared__ unsigned short As[128][40];   // 32 k + 8 pad (16B-aligned rows, 4-way max)
  __shared__ unsigned short Bs[128][40];
  const int tid = threadIdx.x;
  const int bm  = blockIdx.x * 128;
  const int wi  = blockIdx.y >> 1;
  const int bn  = (blockIdx.y & 1) * 128;
  const unsigned short* Wt = WT + wi * 65536;
  unsigned short* O = (wi==0)?Qo:(wi==1)?Ko:(wi==2)?Vo:Go;

  const int lane = tid & 63, wid = tid >> 6;
  const int wm = (wid >> 1) * 64, wn = (wid & 1) * 64;
  const int lr = lane & 31, hi = lane >> 5;
  const int sr = tid >> 1, sc = (tid & 1) * 16;

  f32x16 acc[2][2];
#pragma unroll
  for (int i = 0; i < 2; i++)
#pragma unroll
    for (int j = 0; j < 2; j++)
#pragma unroll
      for (int r = 0; r < 16; r++) acc[i][j][r] = 0.f;

  for (int k0 = 0; k0 < 256; k0 += 32) {
    const uint4* xs = (const uint4*)(X + (size_t)(bm + sr) * 256 + k0 + sc);
    uint4 x0 = xs[0], x1 = xs[1];
    const uint4* wsrc = (const uint4*)(Wt + (size_t)(bn + sr) * 256 + k0 + sc);
    uint4 b0 = wsrc[0], b1 = wsrc[1];
    *(uint4*)&As[sr][sc] = x0; *(uint4*)&As[sr][sc + 8] = x1;
    *(uint4*)&Bs[sr][sc] = b0; *(uint4*)&Bs[sr][sc + 8] = b1;
    __syncthreads();
#pragma unroll
    for (int kh = 0; kh < 2; kh++) {
      s16x8 a0  = *(const s16x8*)&As[wm + lr][kh*16 + 8*hi];
      s16x8 a1  = *(const s16x8*)&As[wm + 32 + lr][kh*16 + 8*hi];
      s16x8 bb0 = *(const s16x8*)&Bs[wn + lr][kh*16 + 8*hi];
      s16x8 bb1 = *(const s16x8*)&Bs[wn + 32 + lr][kh*16 + 8*hi];
      acc[0][0] = MFMA32(a0, bb0, acc[0][0]);
      acc[0][1] = MFMA32(a0, bb1, acc[0][1]);
      acc[1][0] = MFMA32(a1, bb0, acc[1][0]);
      acc[1][1] = MFMA32(a1, bb1, acc[1][1]);
    }
    __syncthreads();
  }

  const float qs = 0.17677669529663687f;   // 32^-0.5
#pragma unroll
  for (int ms = 0; ms < 2; ms++) {
#pragma unroll
    for (int ns = 0; ns < 2; ns++) {
      int colg = bn + wn + ns*32 + lr;
      float bgv = (wi == 3) ? bg[colg] : 0.f;
#pragma unroll
      for (int r = 0; r < 16; r++) {
        float v = acc[ms][ns][r];
        if (wi == 0) v *= qs;
        if (wi == 3) v = 1.0f / (1.0f + __expf(-(v + bgv)));
        int row = bm + wm + ms*32 + (r & 3) + 8*(r >> 2) + 4*hi;
        O[(size_t)row * 256 + colg] = f2bf(v);
      }
    }
  }
}

// ---------------------------------------------------------------------------
// Kernel 3: MFMA flash attention per (s,h). 4 waves x 3 q-strips of 32.
// Swapped QK^T (mfma(K,Q)) -> P lane-local per q-row; defer-max (THR=8);
// cvt_pk + v_permlane32_swap_b32 to form PV A-frags; V transposed in LDS.
// Writes un-gated O (bf16); gate applied in out_gemm staging.
// ---------------------------------------------------------------------------
__global__ __launch_bounds__(256) void attn_kernel(const unsigned short* __restrict__ Qb,
    const unsigned short* __restrict__ Kb, const unsigned short* __restrict__ Vb,
    const float* __restrict__ mask, unsigned short* __restrict__ Ob) {
  __shared__ unsigned short Kl[384][40];   // [k-row][d], padded
  __shared__ unsigned short VT[32][392];   // [d][k-row], padded
  __shared__ float mb[384];
  __shared__ float sAl[4][32];

  const int h = blockIdx.x, s = blockIdx.y;
  const int tid = threadIdx.x;
  const int lane = tid & 63, wid = tid >> 6;
  const int lr = lane & 31, hi = lane >> 5;

  // stage K (copy) and V (transpose)
#pragma unroll
  for (int i = 0; i < 3; i++) {
    int rh = tid + 256*i;
    int r = rh >> 1, c0 = (rh & 1) * 16;
    const unsigned short* ksrc = Kb + ((size_t)(s*R_ + r)) * 256 + h*32 + c0;
    *(uint4*)&Kl[r][c0]     = *(const uint4*)ksrc;
    *(uint4*)&Kl[r][c0 + 8] = *(const uint4*)(ksrc + 8);
    const unsigned short* vsrc = Vb + ((size_t)(s*R_ + r)) * 256 + h*32 + c0;
    unsigned short tmp[16];
    *(uint4*)tmp       = *(const uint4*)vsrc;
    *(uint4*)(tmp + 8) = *(const uint4*)(vsrc + 8);
#pragma unroll
    for (int j = 0; j < 16; j++) VT[c0 + j][r] = tmp[j];
  }
  for (int r = tid; r < 384; r += 256) mb[r] = 1e9f * (mask[s*R_ + r] - 1.0f);

  // Q fragments (B-operand of swapped QK^T): lane holds Q[q0+lr][kh*16+8*hi+j]
  s16x8 bq[3][2];
#pragma unroll
  for (int st = 0; st < 3; st++)
#pragma unroll
    for (int kh = 0; kh < 2; kh++)
      bq[st][kh] = *(const s16x8*)(Qb + ((size_t)(s*R_ + wid*96 + st*32 + lr)) * 256
                                   + h*32 + kh*16 + 8*hi);

  f32x16 of[3];
#pragma unroll
  for (int st = 0; st < 3; st++)
#pragma unroll
    for (int r = 0; r < 16; r++) of[st][r] = 0.f;
  float mrun[3] = {-1e30f, -1e30f, -1e30f};
  float lsum[3] = {0.f, 0.f, 0.f};

  __syncthreads();

  for (int kt = 0; kt < 12; kt++) {
    s16x8 ak0 = *(const s16x8*)&Kl[kt*32 + lr][8*hi];
    s16x8 ak1 = *(const s16x8*)&Kl[kt*32 + lr][16 + 8*hi];
    s16x8 bv0 = *(const s16x8*)&VT[lr][kt*32 + 8*hi];
    s16x8 bv1 = *(const s16x8*)&VT[lr][kt*32 + 16 + 8*hi];
    float mbr[16];
#pragma unroll
    for (int r = 0; r < 16; r++) mbr[r] = mb[kt*32 + (r & 3) + 8*(r >> 2) + 4*hi];

#pragma unroll
    for (int st = 0; st < 3; st++) {
      f32x16 p;
#pragma unroll
      for (int r = 0; r < 16; r++) p[r] = 0.f;
      p = MFMA32(ak0, bq[st][0], p);
      p = MFMA32(ak1, bq[st][1], p);
      float pm = -1e30f;
#pragma unroll
      for (int r = 0; r < 16; r++) { p[r] += mbr[r]; pm = fmaxf(pm, p[r]); }
      pm = fmaxf(pm, __shfl_xor(pm, 32));
      if (!__all(pm <= mrun[st] + 8.0f)) {        // defer-max (T13)
        float nm = fmaxf(mrun[st], pm);
        float al = __expf(mrun[st] - nm);
        mrun[st] = nm;
        lsum[st] *= al;
        if (hi == 0) sAl[wid][lr] = al;           // per-wave slot, no barrier
        float alr[16];
#pragma unroll
        for (int r = 0; r < 16; r++) alr[r] = sAl[wid][(r & 3) + 8*(r >> 2) + 4*hi];
#pragma unroll
        for (int r = 0; r < 16; r++) of[st][r] *= alr[r];
      }
      float ls = 0.f;
#pragma unroll
      for (int r = 0; r < 16; r++) { p[r] = __expf(p[r] - mrun[st]); ls += p[r]; }
      lsum[st] += ls;
      // pack P to bf16 and redistribute halves -> PV A-fragments (T12)
      uint32_t w0 = pkbf(p[0],  p[1]),  w1 = pkbf(p[2],  p[3]);
      uint32_t w2 = pkbf(p[4],  p[5]),  w3 = pkbf(p[6],  p[7]);
      uint32_t w4 = pkbf(p[8],  p[9]),  w5 = pkbf(p[10], p[11]);
      uint32_t w6 = pkbf(p[12], p[13]), w7 = pkbf(p[14], p[15]);
      asm volatile("v_permlane32_swap_b32 %0, %1" : "+v"(w0), "+v"(w2));
      asm volatile("v_permlane32_swap_b32 %0, %1" : "+v"(w1), "+v"(w3));
      asm volatile("v_permlane32_swap_b32 %0, %1" : "+v"(w4), "+v"(w6));
      asm volatile("v_permlane32_swap_b32 %0, %1" : "+v"(w5), "+v"(w7));
      i32x4 pa0i = {(int)w0, (int)w1, (int)w2, (int)w3};
      i32x4 pa1i = {(int)w4, (int)w5, (int)w6, (int)w7};
      of[st] = MFMA32(__builtin_bit_cast(s16x8, pa0i), bv0, of[st]);
      of[st] = MFMA32(__builtin_bit_cast(s16x8, pa1i), bv1, of[st]);
    }
  }

#pragma unroll
  for (int st = 0; st < 3; st++) {
    float lt = lsum[st] + __shfl_xor(lsum[st], 32);
    float inv = 1.0f / lt;
    if (hi == 0) sAl[wid][lr] = inv;
    float ivr[16];
#pragma unroll
    for (int r = 0; r < 16; r++) ivr[r] = sAl[wid][(r & 3) + 8*(r >> 2) + 4*hi];
#pragma unroll
    for (int r = 0; r < 16; r++) {
      int row = wid*96 + st*32 + (r & 3) + 8*(r >> 2) + 4*hi;
      Ob[((size_t)(s*R_ + row)) * 256 + h*32 + lr] = f2bf(of[st][r] * ivr[r]);
    }
  }
}

// ---------------------------------------------------------------------------
// Kernel 4: output GEMM. A = (O .* G) bf16, B = wo^T (prepped). Out fp32 + bo.
// ---------------------------------------------------------------------------
__global__ __launch_bounds__(256) void out_gemm(const unsigned short* __restrict__ Ob,
    const unsigned short* __restrict__ Gb, const unsigned short* __restrict__ WT,
    const float* __restrict__ bo, float* __restrict__ Out) {
  __shared__ unsigned short As[128][40];
  __shared__ unsigned short Bs[128][40];
  const unsigned short* Wt = WT + 4 * 65536;
  const int tid = threadIdx.x;
  const int bm = blockIdx.x * 128;
  const int bn = blockIdx.y * 128;
  const int lane = tid & 63, wid = tid >> 6;
  const int wm = (wid >> 1) * 64, wn = (wid & 1) * 64;
  const int lr = lane & 31, hi = lane >> 5;
  const int sr = tid >> 1, sc = (tid & 1) * 16;

  f32x16 acc[2][2];
#pragma unroll
  for (int i = 0; i < 2; i++)
#pragma unroll
    for (int j = 0; j < 2; j++)
#pragma unroll
      for (int r = 0; r < 16; r++) acc[i][j][r] = 0.f;

  for (int k0 = 0; k0 < 256; k0 += 32) {
    const unsigned short* orow = Ob + (size_t)(bm + sr) * 256 + k0 + sc;
    const unsigned short* grow = Gb + (size_t)(bm + sr) * 256 + k0 + sc;
    unsigned short ot[16], gt[16], res[16];
    *(uint4*)ot       = *(const uint4*)orow;
    *(uint4*)(ot + 8) = *(const uint4*)(orow + 8);
    *(uint4*)gt       = *(const uint4*)grow;
    *(uint4*)(gt + 8) = *(const uint4*)(grow + 8);
#pragma unroll
    for (int j = 0; j < 16; j++) res[j] = f2bf(bf2f(ot[j]) * bf2f(gt[j]));
    const uint4* wsrc = (const uint4*)(Wt + (size_t)(bn + sr) * 256 + k0 + sc);
    uint4 b0 = wsrc[0], b1 = wsrc[1];
    *(uint4*)&As[sr][sc] = *(uint4*)res; *(uint4*)&As[sr][sc + 8] = *(uint4*)(res + 8);
    *(uint4*)&Bs[sr][sc] = b0;           *(uint4*)&Bs[sr][sc + 8] = b1;
    __syncthreads();
#pragma unroll
    for (int kh = 0; kh < 2; kh++) {
      s16x8 a0  = *(const s16x8*)&As[wm + lr][kh*16 + 8*hi];
      s16x8 a1  = *(const s16x8*)&As[wm + 32 + lr][kh*16 + 8*hi];
      s16x8 bb0 = *(const s16x8*)&Bs[wn + lr][kh*16 + 8*hi];
      s16x8 bb1 = *(const s16x8*)&Bs[wn + 32 + lr][kh*16 + 8*hi];
      acc[0][0] = MFMA32(a0, bb0, acc[0][0]);
      acc[0][1] = MFMA32(a0, bb1, acc[0][1]);
      acc[1][0] = MFMA32(a1, bb0, acc[1][0]);
      acc[1][1] = MFMA32(a1, bb1, acc[1][1]);
    }
    __syncthreads();
  }

#pragma unroll
  for (int ms = 0; ms < 2; ms++) {
#pragma unroll
    for (int ns = 0; ns < 2; ns++) {
      int colg = bn + wn + ns*32 + lr;
      float bov = bo[colg];
#pragma unroll
      for (int r = 0; r < 16; r++) {
        int row = bm + wm + ms*32 + (r & 3) + 8*(r >> 2) + 4*hi;
        Out[(size_t)row * 256 + colg] = acc[ms][ns][r] + bov;
      }
    }
  }
}

// ---------------------------------------------------------------------------
// Host launcher
// ---------------------------------------------------------------------------
extern "C" void kernel_launch(void* const* d_in, const int* in_sizes, int n_in,
                              void* d_out, int out_size, void* d_ws, size_t ws_size,
                              hipStream_t stream) {
  const float* m    = (const float*)d_in[0];
  const float* mask = (const float*)d_in[1];
  const float* ln_w = (const float*)d_in[2];
  const float* ln_b = (const float*)d_in[3];
  const float* wq   = (const float*)d_in[4];
  const float* wk   = (const float*)d_in[5];
  const float* wv   = (const float*)d_in[6];
  const float* wg   = (const float*)d_in[7];
  const float* bg   = (const float*)d_in[8];
  const float* wo   = (const float*)d_in[9];
  const float* bo   = (const float*)d_in[10];
  float* out = (float*)d_out;

  // ws (ushort elems): xbf | qb | kb | vb | gb | ob | WT(5x65536)  = ~152 MB
  unsigned short* ws = (unsigned short*)d_ws;
  const size_t SZ = (size_t)M_ * 256;
  unsigned short* xbf = ws;
  unsigned short* qb  = ws + 1 * SZ;
  unsigned short* kb  = ws + 2 * SZ;
  unsigned short* vb  = ws + 3 * SZ;
  unsigned short* gb  = ws + 4 * SZ;
  unsigned short* ob  = ws + 5 * SZ;
  unsigned short* WT  = ws + 6 * SZ;

  prep_w<<<1280, 256, 0, stream>>>(wq, wk, wv, wg, wo, WT);
  ln_kernel<<<M_ / 4, 256, 0, stream>>>(m, ln_w, ln_b, xbf);
  proj_gemm<<<dim3(M_ / 128, 8), 256, 0, stream>>>(xbf, WT, bg, qb, kb, vb, gb);
  attn_kernel<<<dim3(H_, S_), 256, 0, stream>>>(qb, kb, vb, mask, ob);
  out_gemm<<<dim3(M_ / 128, 2), 256, 0, stream>>>(ob, gb, WT, bo, out);
}

// Round 3
// 262.332 us; speedup vs baseline: 4.1077x; 1.0313x over previous
//
#include <hip/hip_runtime.h>
#include <cstdint>
#include <cstddef>

// MSA row attention (openfold-style), bf16 MFMA pipeline v3.
#define S_  128
#define R_  384
#define C_  256
#define H_  8
#define D_  32
#define HD_ 256
#define M_  (S_*R_)      // 49152

#define LOG2E 1.4426950408889634f

typedef float f32x16 __attribute__((ext_vector_type(16)));
typedef short s16x8  __attribute__((ext_vector_type(8)));
typedef int   i32x4  __attribute__((ext_vector_type(4)));

__device__ __forceinline__ unsigned short f2bf(float f) {
  uint32_t u = __float_as_uint(f);
  u += 0x7fffu + ((u >> 16) & 1u);
  return (unsigned short)(u >> 16);
}
__device__ __forceinline__ float bf2f(unsigned short s) {
  return __uint_as_float(((uint32_t)s) << 16);
}
__device__ __forceinline__ uint32_t pkbf(float lo, float hi) {
  return (uint32_t)f2bf(lo) | ((uint32_t)f2bf(hi) << 16);
}
#define MFMA32(a,b,c) __builtin_amdgcn_mfma_f32_32x32x16_bf16((a),(b),(c),0,0,0)

// global -> LDS direct copy, 16B per lane (lane offset added by HW).
__device__ __forceinline__ void gload16(const void* g, void* l) {
  __builtin_amdgcn_global_load_lds(
      (const __attribute__((address_space(1))) void*)g,
      (__attribute__((address_space(3))) void*)l, 16, 0, 0);
}

// ---------------------------------------------------------------------------
// Kernel 0: weight prep — LDS-tiled transpose + cvt bf16. WT[mat][n][k].
// mats 0..3 = wq,wk,wv,wg; 4 = wo. All 256x256.
// ---------------------------------------------------------------------------
__global__ __launch_bounds__(256) void prep_w(const float* __restrict__ wq,
    const float* __restrict__ wk, const float* __restrict__ wv,
    const float* __restrict__ wg, const float* __restrict__ wo,
    unsigned short* __restrict__ WT) {
  __shared__ unsigned short Tl[64][72];
  const int mat = blockIdx.x >> 4;
  const int t   = blockIdx.x & 15;
  const int k0  = (t >> 2) * 64, n0 = (t & 3) * 64;
  const float* W = (mat==0)?wq:(mat==1)?wk:(mat==2)?wv:(mat==3)?wg:wo;
  const int tx = threadIdx.x & 63, ty = threadIdx.x >> 6;
#pragma unroll
  for (int i = 0; i < 16; i++) {
    int kk = ty + i * 4;
    Tl[tx][kk] = f2bf(W[(size_t)(k0 + kk) * 256 + n0 + tx]);   // coalesced read
  }
  __syncthreads();
#pragma unroll
  for (int i = 0; i < 16; i++) {
    int nn = ty + i * 4;
    WT[(size_t)mat * 65536 + (size_t)(n0 + nn) * 256 + k0 + tx] = Tl[nn][tx];
  }
}

// ---------------------------------------------------------------------------
// Kernel 1: LayerNorm over C=256, one wave per row, writes bf16.
// ---------------------------------------------------------------------------
__global__ __launch_bounds__(256) void ln_kernel(const float* __restrict__ mIn,
    const float* __restrict__ w, const float* __restrict__ b,
    unsigned short* __restrict__ x) {
  int row  = blockIdx.x * 4 + (threadIdx.x >> 6);
  int lane = threadIdx.x & 63;
  const float4 v4 = *(const float4*)(mIn + (size_t)row * C_ + lane * 4);
  float s  = v4.x + v4.y + v4.z + v4.w;
  float ss = v4.x*v4.x + v4.y*v4.y + v4.z*v4.z + v4.w*v4.w;
#pragma unroll
  for (int off = 32; off > 0; off >>= 1) {
    s  += __shfl_xor(s,  off);
    ss += __shfl_xor(ss, off);
  }
  float mu  = s * (1.0f / C_);
  float var = ss * (1.0f / C_) - mu * mu;
  float rs  = rsqrtf(var + 1e-5f);
  const float4 wv = *(const float4*)(w + lane * 4);
  const float4 bv = *(const float4*)(b + lane * 4);
  uint2 o2;
  o2.x = pkbf((v4.x - mu) * rs * wv.x + bv.x, (v4.y - mu) * rs * wv.y + bv.y);
  o2.y = pkbf((v4.z - mu) * rs * wv.z + bv.z, (v4.w - mu) * rs * wv.w + bv.w);
  *(uint2*)(x + (size_t)row * C_ + lane * 4) = o2;
}

// ---------------------------------------------------------------------------
// Kernel 2: fused QKVG projection. m97 structure: 128x128 tile, BK=32,
// global_load_lds x16, linear LDS. 4 waves, 2x2 MFMA32 each.
// Epilogue: Q *= D^-0.5 * log2e (exp2-domain attn); G = sigmoid(G + bg).
// ---------------------------------------------------------------------------
__global__ __launch_bounds__(256) void proj_gemm(const unsigned short* __restrict__ X,
    const unsigned short* __restrict__ WT, const float* __restrict__ bg,
    unsigned short* __restrict__ Qo, unsigned short* __restrict__ Ko,
    unsigned short* __restrict__ Vo, unsigned short* __restrict__ Go) {
  __shared__ __align__(16) unsigned short As[128 * 32];
  __shared__ __align__(16) unsigned short Bs[128 * 32];
  const int tid = threadIdx.x;
  const int bm  = blockIdx.x * 128;
  const int wi  = blockIdx.y >> 1;
  const int bn  = (blockIdx.y & 1) * 128;
  const unsigned short* Wt = WT + (size_t)wi * 65536;
  unsigned short* O = (wi==0)?Qo:(wi==1)?Ko:(wi==2)?Vo:Go;

  const int lane = tid & 63, wid = tid >> 6;
  const int wm = (wid >> 1) * 64, wn = (wid & 1) * 64;
  const int lr = lane & 31, hi = lane >> 5;
  const int srow = lane >> 2, scol = (lane & 3) * 8;   // staging: lane -> row/col

  f32x16 acc[2][2];
#pragma unroll
  for (int i = 0; i < 2; i++)
#pragma unroll
    for (int j = 0; j < 2; j++)
#pragma unroll
      for (int r = 0; r < 16; r++) acc[i][j][r] = 0.f;

  for (int k0 = 0; k0 < 256; k0 += 32) {
#pragma unroll
    for (int i = 0; i < 2; i++) {
      const int rbase = wid * 32 + i * 16;             // 16-row chunk per instr
      gload16(X  + (size_t)(bm + rbase + srow) * 256 + k0 + scol, &As[rbase * 32]);
      gload16(Wt + (size_t)(bn + rbase + srow) * 256 + k0 + scol, &Bs[rbase * 32]);
    }
    asm volatile("s_waitcnt vmcnt(0)" ::: "memory");
    __syncthreads();
#pragma unroll
    for (int kh = 0; kh < 2; kh++) {
      s16x8 a0 = *(const s16x8*)&As[(wm + lr) * 32      + kh*16 + 8*hi];
      s16x8 a1 = *(const s16x8*)&As[(wm + 32 + lr) * 32 + kh*16 + 8*hi];
      s16x8 b0 = *(const s16x8*)&Bs[(wn + lr) * 32      + kh*16 + 8*hi];
      s16x8 b1 = *(const s16x8*)&Bs[(wn + 32 + lr) * 32 + kh*16 + 8*hi];
      acc[0][0] = MFMA32(a0, b0, acc[0][0]);
      acc[0][1] = MFMA32(a0, b1, acc[0][1]);
      acc[1][0] = MFMA32(a1, b0, acc[1][0]);
      acc[1][1] = MFMA32(a1, b1, acc[1][1]);
    }
    __syncthreads();
  }

  const float qs2 = 0.17677669529663687f * LOG2E;   // D^-0.5 * log2e
#pragma unroll
  for (int ms = 0; ms < 2; ms++) {
#pragma unroll
    for (int ns = 0; ns < 2; ns++) {
      int colg = bn + wn + ns*32 + lr;
      float bgv = (wi == 3) ? bg[colg] : 0.f;
#pragma unroll
      for (int r = 0; r < 16; r++) {
        float v = acc[ms][ns][r];
        if (wi == 0) v *= qs2;
        if (wi == 3) v = 1.0f / (1.0f + __expf(-(v + bgv)));
        int row = bm + wm + ms*32 + (r & 3) + 8*(r >> 2) + 4*hi;
        O[(size_t)row * 256 + colg] = f2bf(v);
      }
    }
  }
}

// ---------------------------------------------------------------------------
// Kernel 3: MFMA flash attention per (s,h), exp2-domain softmax.
// K/V staged in 2 halves of 192 rows (30 KB LDS -> 4 blocks/CU resident).
// Swapped QK^T; mask bias pre-loaded into accumulator; defer-max;
// cvt_pk + permlane32_swap P-repack; gate fused into epilogue.
// ---------------------------------------------------------------------------
__global__ __launch_bounds__(256) void attn_kernel(const unsigned short* __restrict__ Qb,
    const unsigned short* __restrict__ Kb, const unsigned short* __restrict__ Vb,
    const unsigned short* __restrict__ Gb, const float* __restrict__ mask,
    unsigned short* __restrict__ Ob) {
  __shared__ unsigned short Kl[192][40];   // [k-row-local][d] (padded, 16B rows)
  __shared__ unsigned short VT[32][200];   // [d][k-row-local] (padded)
  __shared__ float mb[384];
  __shared__ float sAl[4][32];

  const int h = blockIdx.x, s = blockIdx.y;
  const int tid = threadIdx.x;
  const int wid = tid >> 6;
  const int lane = tid & 63;
  const int lr = lane & 31, hi = lane >> 5;

  for (int r = tid; r < 384; r += 256)
    mb[r] = (1e9f * LOG2E) * (mask[s * R_ + r] - 1.0f);

  // Q fragments (B-operand of swapped QK^T), pre-scaled by D^-0.5*log2e in proj
  s16x8 bq[3][2];
#pragma unroll
  for (int st = 0; st < 3; st++)
#pragma unroll
    for (int kh = 0; kh < 2; kh++)
      bq[st][kh] = *(const s16x8*)(Qb + ((size_t)(s*R_ + wid*96 + st*32 + lr)) * 256
                                   + h*32 + kh*16 + 8*hi);

  f32x16 of[3];
#pragma unroll
  for (int st = 0; st < 3; st++)
#pragma unroll
    for (int r = 0; r < 16; r++) of[st][r] = 0.f;
  float mrun[3] = {-1e30f, -1e30f, -1e30f};
  float lsum[3] = {0.f, 0.f, 0.f};

  for (int ph = 0; ph < 2; ph++) {
    __syncthreads();
    // stage rows [ph*192, ph*192+192): K copy + V transpose
#pragma unroll
    for (int i = 0; i < 2; i++) {
      int rh = tid + 256 * i;
      if (rh < 384) {
        int rl = rh >> 1, c0 = (rh & 1) * 16;
        int rg = ph * 192 + rl;
        const unsigned short* ksrc = Kb + ((size_t)(s*R_ + rg)) * 256 + h*32 + c0;
        *(uint4*)&Kl[rl][c0]     = *(const uint4*)ksrc;
        *(uint4*)&Kl[rl][c0 + 8] = *(const uint4*)(ksrc + 8);
        const unsigned short* vsrc = Vb + ((size_t)(s*R_ + rg)) * 256 + h*32 + c0;
        unsigned short tmp[16];
        *(uint4*)tmp       = *(const uint4*)vsrc;
        *(uint4*)(tmp + 8) = *(const uint4*)(vsrc + 8);
#pragma unroll
        for (int j = 0; j < 16; j++) VT[c0 + j][rl] = tmp[j];
      }
    }
    __syncthreads();

    for (int kt = 0; kt < 6; kt++) {
      const int ktg = ph * 6 + kt;
      s16x8 ak0 = *(const s16x8*)&Kl[kt*32 + lr][8*hi];
      s16x8 ak1 = *(const s16x8*)&Kl[kt*32 + lr][16 + 8*hi];
      s16x8 bv0 = *(const s16x8*)&VT[lr][kt*32 + 8*hi];
      s16x8 bv1 = *(const s16x8*)&VT[lr][kt*32 + 16 + 8*hi];
      float mbr[16];
#pragma unroll
      for (int r = 0; r < 16; r++) mbr[r] = mb[ktg*32 + (r & 3) + 8*(r >> 2) + 4*hi];

#pragma unroll
      for (int st = 0; st < 3; st++) {
        f32x16 p;
#pragma unroll
        for (int r = 0; r < 16; r++) p[r] = mbr[r];   // bias pre-loaded into acc
        __builtin_amdgcn_s_setprio(1);
        p = MFMA32(ak0, bq[st][0], p);
        p = MFMA32(ak1, bq[st][1], p);
        __builtin_amdgcn_s_setprio(0);
        // max over 16 regs (tree -> v_max3 fusion) + cross-half
        float m01 = fmaxf(fmaxf(p[0], p[1]), fmaxf(p[2], p[3]));
        float m23 = fmaxf(fmaxf(p[4], p[5]), fmaxf(p[6], p[7]));
        float m45 = fmaxf(fmaxf(p[8], p[9]), fmaxf(p[10], p[11]));
        float m67 = fmaxf(fmaxf(p[12], p[13]), fmaxf(p[14], p[15]));
        float pm = fmaxf(fmaxf(m01, m23), fmaxf(m45, m67));
        pm = fmaxf(pm, __shfl_xor(pm, 32));
        if (!__all(pm <= mrun[st] + 11.54f)) {        // defer-max (log2 units)
          float nm = fmaxf(mrun[st], pm);
          float al = __builtin_amdgcn_exp2f(mrun[st] - nm);
          mrun[st] = nm;
          lsum[st] *= al;
          if (hi == 0) sAl[wid][lr] = al;
          float alr[16];
#pragma unroll
          for (int r = 0; r < 16; r++) alr[r] = sAl[wid][(r & 3) + 8*(r >> 2) + 4*hi];
#pragma unroll
          for (int r = 0; r < 16; r++) of[st][r] *= alr[r];
        }
        float ls = 0.f;
#pragma unroll
        for (int r = 0; r < 16; r++) {
          p[r] = __builtin_amdgcn_exp2f(p[r] - mrun[st]);
          ls += p[r];
        }
        lsum[st] += ls;
        // pack P to bf16, swap halves -> PV A-fragments
        uint32_t w0 = pkbf(p[0],  p[1]),  w1 = pkbf(p[2],  p[3]);
        uint32_t w2 = pkbf(p[4],  p[5]),  w3 = pkbf(p[6],  p[7]);
        uint32_t w4 = pkbf(p[8],  p[9]),  w5 = pkbf(p[10], p[11]);
        uint32_t w6 = pkbf(p[12], p[13]), w7 = pkbf(p[14], p[15]);
        asm volatile("v_permlane32_swap_b32 %0, %1" : "+v"(w0), "+v"(w2));
        asm volatile("v_permlane32_swap_b32 %0, %1" : "+v"(w1), "+v"(w3));
        asm volatile("v_permlane32_swap_b32 %0, %1" : "+v"(w4), "+v"(w6));
        asm volatile("v_permlane32_swap_b32 %0, %1" : "+v"(w5), "+v"(w7));
        i32x4 pa0i = {(int)w0, (int)w1, (int)w2, (int)w3};
        i32x4 pa1i = {(int)w4, (int)w5, (int)w6, (int)w7};
        __builtin_amdgcn_s_setprio(1);
        of[st] = MFMA32(__builtin_bit_cast(s16x8, pa0i), bv0, of[st]);
        of[st] = MFMA32(__builtin_bit_cast(s16x8, pa1i), bv1, of[st]);
        __builtin_amdgcn_s_setprio(0);
      }
    }
  }

#pragma unroll
  for (int st = 0; st < 3; st++) {
    float lt = lsum[st] + __shfl_xor(lsum[st], 32);
    float inv = 1.0f / lt;
    if (hi == 0) sAl[wid][lr] = inv;
    float ivr[16];
#pragma unroll
    for (int r = 0; r < 16; r++) ivr[r] = sAl[wid][(r & 3) + 8*(r >> 2) + 4*hi];
#pragma unroll
    for (int r = 0; r < 16; r++) {
      int row = wid*96 + st*32 + (r & 3) + 8*(r >> 2) + 4*hi;
      size_t off = ((size_t)(s*R_ + row)) * 256 + h*32 + lr;
      float gv = bf2f(Gb[off]);                       // gate fused here
      Ob[off] = f2bf(of[st][r] * ivr[r] * gv);
    }
  }
}

// ---------------------------------------------------------------------------
// Kernel 4: output GEMM. A = gated O (bf16, pure copy -> global_load_lds),
// B = wo^T. Out fp32 + bo. Same m97 structure as proj.
// ---------------------------------------------------------------------------
__global__ __launch_bounds__(256) void out_gemm(const unsigned short* __restrict__ Ob,
    const unsigned short* __restrict__ WT, const float* __restrict__ bo,
    float* __restrict__ Out) {
  __shared__ __align__(16) unsigned short As[128 * 32];
  __shared__ __align__(16) unsigned short Bs[128 * 32];
  const unsigned short* Wt = WT + 4 * 65536;
  const int tid = threadIdx.x;
  const int bm = blockIdx.x * 128;
  const int bn = blockIdx.y * 128;
  const int lane = tid & 63, wid = tid >> 6;
  const int wm = (wid >> 1) * 64, wn = (wid & 1) * 64;
  const int lr = lane & 31, hi = lane >> 5;
  const int srow = lane >> 2, scol = (lane & 3) * 8;

  f32x16 acc[2][2];
#pragma unroll
  for (int i = 0; i < 2; i++)
#pragma unroll
    for (int j = 0; j < 2; j++)
#pragma unroll
      for (int r = 0; r < 16; r++) acc[i][j][r] = 0.f;

  for (int k0 = 0; k0 < 256; k0 += 32) {
#pragma unroll
    for (int i = 0; i < 2; i++) {
      const int rbase = wid * 32 + i * 16;
      gload16(Ob + (size_t)(bm + rbase + srow) * 256 + k0 + scol, &As[rbase * 32]);
      gload16(Wt + (size_t)(bn + rbase + srow) * 256 + k0 + scol, &Bs[rbase * 32]);
    }
    asm volatile("s_waitcnt vmcnt(0)" ::: "memory");
    __syncthreads();
#pragma unroll
    for (int kh = 0; kh < 2; kh++) {
      s16x8 a0 = *(const s16x8*)&As[(wm + lr) * 32      + kh*16 + 8*hi];
      s16x8 a1 = *(const s16x8*)&As[(wm + 32 + lr) * 32 + kh*16 + 8*hi];
      s16x8 b0 = *(const s16x8*)&Bs[(wn + lr) * 32      + kh*16 + 8*hi];
      s16x8 b1 = *(const s16x8*)&Bs[(wn + 32 + lr) * 32 + kh*16 + 8*hi];
      acc[0][0] = MFMA32(a0, b0, acc[0][0]);
      acc[0][1] = MFMA32(a0, b1, acc[0][1]);
      acc[1][0] = MFMA32(a1, b0, acc[1][0]);
      acc[1][1] = MFMA32(a1, b1, acc[1][1]);
    }
    __syncthreads();
  }

#pragma unroll
  for (int ms = 0; ms < 2; ms++) {
#pragma unroll
    for (int ns = 0; ns < 2; ns++) {
      int colg = bn + wn + ns*32 + lr;
      float bov = bo[colg];
#pragma unroll
      for (int r = 0; r < 16; r++) {
        int row = bm + wm + ms*32 + (r & 3) + 8*(r >> 2) + 4*hi;
        Out[(size_t)row * 256 + colg] = acc[ms][ns][r] + bov;
      }
    }
  }
}

// ---------------------------------------------------------------------------
// Host launcher
// ---------------------------------------------------------------------------
extern "C" void kernel_launch(void* const* d_in, const int* in_sizes, int n_in,
                              void* d_out, int out_size, void* d_ws, size_t ws_size,
                              hipStream_t stream) {
  const float* m    = (const float*)d_in[0];
  const float* mask = (const float*)d_in[1];
  const float* ln_w = (const float*)d_in[2];
  const float* ln_b = (const float*)d_in[3];
  const float* wq   = (const float*)d_in[4];
  const float* wk   = (const float*)d_in[5];
  const float* wv   = (const float*)d_in[6];
  const float* wg   = (const float*)d_in[7];
  const float* bg   = (const float*)d_in[8];
  const float* wo   = (const float*)d_in[9];
  const float* bo   = (const float*)d_in[10];
  float* out = (float*)d_out;

  // ws (ushort elems): xbf | qb | kb | vb | gb | ob | WT(5x65536)
  unsigned short* ws = (unsigned short*)d_ws;
  const size_t SZ = (size_t)M_ * 256;
  unsigned short* xbf = ws;
  unsigned short* qb  = ws + 1 * SZ;
  unsigned short* kb  = ws + 2 * SZ;
  unsigned short* vb  = ws + 3 * SZ;
  unsigned short* gb  = ws + 4 * SZ;
  unsigned short* ob  = ws + 5 * SZ;
  unsigned short* WT  = ws + 6 * SZ;

  prep_w<<<80, 256, 0, stream>>>(wq, wk, wv, wg, wo, WT);
  ln_kernel<<<M_ / 4, 256, 0, stream>>>(m, ln_w, ln_b, xbf);
  proj_gemm<<<dim3(M_ / 128, 8), 256, 0, stream>>>(xbf, WT, bg, qb, kb, vb, gb);
  attn_kernel<<<dim3(H_, S_), 256, 0, stream>>>(qb, kb, vb, gb, mask, ob);
  out_gemm<<<dim3(M_ / 128, 2), 256, 0, stream>>>(ob, WT, bo, out);
}

// Round 5
// 241.421 us; speedup vs baseline: 4.4635x; 1.0866x over previous
//
#include <hip/hip_runtime.h>
#include <cstdint>
#include <cstddef>

// MSA row attention (openfold-style), bf16 MFMA pipeline v4.
#define S_  128
#define R_  384
#define C_  256
#define H_  8
#define D_  32
#define HD_ 256
#define M_  (S_*R_)      // 49152

#define LOG2E 1.4426950408889634f

typedef float f32x16 __attribute__((ext_vector_type(16)));
typedef short s16x8  __attribute__((ext_vector_type(8)));
typedef int   i32x4  __attribute__((ext_vector_type(4)));

__device__ __forceinline__ unsigned short f2bf(float f) {
  uint32_t u = __float_as_uint(f);
  u += 0x7fffu + ((u >> 16) & 1u);
  return (unsigned short)(u >> 16);
}
__device__ __forceinline__ float bf2f(unsigned short s) {
  return __uint_as_float(((uint32_t)s) << 16);
}
__device__ __forceinline__ uint32_t pkbf(float lo, float hi) {
  return (uint32_t)f2bf(lo) | ((uint32_t)f2bf(hi) << 16);
}
#define MFMA32(a,b,c) __builtin_amdgcn_mfma_f32_32x32x16_bf16((a),(b),(c),0,0,0)

__device__ __forceinline__ void gload16(const void* g, void* l) {
  __builtin_amdgcn_global_load_lds(
      (const __attribute__((address_space(1))) void*)g,
      (__attribute__((address_space(3))) void*)l, 16, 0, 0);
}

// ---------------------------------------------------------------------------
// Kernel 0: weight prep — LDS-tiled transpose + cvt bf16. WT[mat][n][k].
// ---------------------------------------------------------------------------
__global__ __launch_bounds__(256) void prep_w(const float* __restrict__ wq,
    const float* __restrict__ wk, const float* __restrict__ wv,
    const float* __restrict__ wg, const float* __restrict__ wo,
    unsigned short* __restrict__ WT) {
  __shared__ unsigned short Tl[64][72];
  const int mat = blockIdx.x >> 4;
  const int t   = blockIdx.x & 15;
  const int k0  = (t >> 2) * 64, n0 = (t & 3) * 64;
  const float* W = (mat==0)?wq:(mat==1)?wk:(mat==2)?wv:(mat==3)?wg:wo;
  const int tx = threadIdx.x & 63, ty = threadIdx.x >> 6;
#pragma unroll
  for (int i = 0; i < 16; i++) {
    int kk = ty + i * 4;
    Tl[tx][kk] = f2bf(W[(size_t)(k0 + kk) * 256 + n0 + tx]);
  }
  __syncthreads();
#pragma unroll
  for (int i = 0; i < 16; i++) {
    int nn = ty + i * 4;
    WT[(size_t)mat * 65536 + (size_t)(n0 + nn) * 256 + k0 + tx] = Tl[nn][tx];
  }
}

// ---------------------------------------------------------------------------
// Kernel 1: LayerNorm over C=256, one wave per row, writes bf16.
// ---------------------------------------------------------------------------
__global__ __launch_bounds__(256) void ln_kernel(const float* __restrict__ mIn,
    const float* __restrict__ w, const float* __restrict__ b,
    unsigned short* __restrict__ x) {
  int row  = blockIdx.x * 4 + (threadIdx.x >> 6);
  int lane = threadIdx.x & 63;
  const float4 v4 = *(const float4*)(mIn + (size_t)row * C_ + lane * 4);
  float s  = v4.x + v4.y + v4.z + v4.w;
  float ss = v4.x*v4.x + v4.y*v4.y + v4.z*v4.z + v4.w*v4.w;
#pragma unroll
  for (int off = 32; off > 0; off >>= 1) {
    s  += __shfl_xor(s,  off);
    ss += __shfl_xor(ss, off);
  }
  float mu  = s * (1.0f / C_);
  float var = ss * (1.0f / C_) - mu * mu;
  float rs  = rsqrtf(var + 1e-5f);
  const float4 wv = *(const float4*)(w + lane * 4);
  const float4 bv = *(const float4*)(b + lane * 4);
  uint2 o2;
  o2.x = pkbf((v4.x - mu) * rs * wv.x + bv.x, (v4.y - mu) * rs * wv.y + bv.y);
  o2.y = pkbf((v4.z - mu) * rs * wv.z + bv.z, (v4.w - mu) * rs * wv.w + bv.w);
  *(uint2*)(x + (size_t)row * C_ + lane * 4) = o2;
}

// ---------------------------------------------------------------------------
// Kernel 2: fused QKVG projection. 64x128 tile, BK=32, global_load_lds x16,
// linear LDS. 4 waves (2m x 2n), acc[1][2] (32 AGPR) for occupancy.
// grid (8, 768): x = {weight, n-half} fast-varying -> same-X blocks adjacent.
// ---------------------------------------------------------------------------
__global__ __launch_bounds__(256, 5) void proj_gemm(const unsigned short* __restrict__ X,
    const unsigned short* __restrict__ WT, const float* __restrict__ bg,
    unsigned short* __restrict__ Qo, unsigned short* __restrict__ Ko,
    unsigned short* __restrict__ Vo, unsigned short* __restrict__ Go) {
  __shared__ __align__(16) unsigned short As[64 * 32];
  __shared__ __align__(16) unsigned short Bs[128 * 32];
  const int tid = threadIdx.x;
  const int wi  = blockIdx.x >> 1;
  const int bn  = (blockIdx.x & 1) * 128;
  const int bm  = blockIdx.y * 64;
  const unsigned short* Wt = WT + (size_t)wi * 65536;
  unsigned short* O = (wi==0)?Qo:(wi==1)?Ko:(wi==2)?Vo:Go;

  const int lane = tid & 63, wid = tid >> 6;
  const int wr = (wid >> 1) * 32, wc = (wid & 1) * 64;
  const int lr = lane & 31, hi = lane >> 5;
  const int srow = lane >> 2, scol = (lane & 3) * 8;

  f32x16 acc0, acc1;
#pragma unroll
  for (int r = 0; r < 16; r++) { acc0[r] = 0.f; acc1[r] = 0.f; }

  for (int k0 = 0; k0 < 256; k0 += 32) {
    gload16(X + (size_t)(bm + wid*16 + srow) * 256 + k0 + scol, &As[wid * 512]);
#pragma unroll
    for (int i = 0; i < 2; i++) {
      const int rb = wid * 32 + i * 16;
      gload16(Wt + (size_t)(bn + rb + srow) * 256 + k0 + scol, &Bs[rb * 32]);
    }
    asm volatile("s_waitcnt vmcnt(0)" ::: "memory");
    __syncthreads();
#pragma unroll
    for (int kh = 0; kh < 2; kh++) {
      s16x8 a0 = *(const s16x8*)&As[(wr + lr) * 32      + kh*16 + 8*hi];
      s16x8 b0 = *(const s16x8*)&Bs[(wc + lr) * 32      + kh*16 + 8*hi];
      s16x8 b1 = *(const s16x8*)&Bs[(wc + 32 + lr) * 32 + kh*16 + 8*hi];
      acc0 = MFMA32(a0, b0, acc0);
      acc1 = MFMA32(a0, b1, acc1);
    }
    __syncthreads();
  }

  const float qs2 = 0.17677669529663687f * LOG2E;
#pragma unroll
  for (int ns = 0; ns < 2; ns++) {
    const f32x16& a = ns ? acc1 : acc0;
    int colg = bn + wc + ns*32 + lr;
    float bgv = (wi == 3) ? bg[colg] : 0.f;
#pragma unroll
    for (int r = 0; r < 16; r++) {
      float v = a[r];
      if (wi == 0) v *= qs2;
      if (wi == 3) v = 1.0f / (1.0f + __expf(-(v + bgv)));
      int row = bm + wr + (r & 3) + 8*(r >> 2) + 4*hi;
      O[(size_t)row * 256 + colg] = f2bf(v);
    }
  }
}

// ---------------------------------------------------------------------------
// Kernel 3: MFMA flash attention per (s,h). 12 waves x 1 q-strip of 32.
// Full K/V staged once (58.8 KB LDS, 2 blocks/CU = 24 waves target).
// Swapped QK^T; exp2-domain; defer-max; v_cvt_pk_bf16_f32 + permlane32_swap.
// ---------------------------------------------------------------------------
__global__ __launch_bounds__(768, 6) void attn_kernel(const unsigned short* __restrict__ Qb,
    const unsigned short* __restrict__ Kb, const unsigned short* __restrict__ Vb,
    const unsigned short* __restrict__ Gb, const float* __restrict__ mask,
    unsigned short* __restrict__ Ob) {
  __shared__ unsigned short Kl[384][40];   // [k-row][d], 80B stride
  __shared__ unsigned short VT[32][392];   // [d][k-row]
  __shared__ float mb[384];
  __shared__ float sAl[12][32];

  const int h = blockIdx.x, s = blockIdx.y;
  const int tid = threadIdx.x;
  const int wid = tid >> 6, lane = tid & 63;
  const int lr = lane & 31, hi = lane >> 5;

  // Staging: threads [0,384) -> K row t (4x b128 LDS writes, contiguous);
  //          threads [384,768) -> V row t-384 (32 scalar writes, each instr
  //          contiguous across lanes -> conflict-free).
  if (tid < 384) {
    const unsigned short* ksrc = Kb + ((size_t)(s*R_ + tid)) * 256 + h*32;
    uint4 k0 = *(const uint4*)ksrc;
    uint4 k1 = *(const uint4*)(ksrc + 8);
    uint4 k2 = *(const uint4*)(ksrc + 16);
    uint4 k3 = *(const uint4*)(ksrc + 24);
    *(uint4*)&Kl[tid][0]  = k0;
    *(uint4*)&Kl[tid][8]  = k1;
    *(uint4*)&Kl[tid][16] = k2;
    *(uint4*)&Kl[tid][24] = k3;
    mb[tid] = (1e9f * LOG2E) * (mask[s * R_ + tid] - 1.0f);
  } else {
    const int r = tid - 384;
    const unsigned short* vsrc = Vb + ((size_t)(s*R_ + r)) * 256 + h*32;
    unsigned short tmp[32];
    *(uint4*)(tmp)      = *(const uint4*)vsrc;
    *(uint4*)(tmp + 8)  = *(const uint4*)(vsrc + 8);
    *(uint4*)(tmp + 16) = *(const uint4*)(vsrc + 16);
    *(uint4*)(tmp + 24) = *(const uint4*)(vsrc + 24);
#pragma unroll
    for (int j = 0; j < 32; j++) VT[j][r] = tmp[j];
  }

  // Q fragments for this wave's strip (B-operand of swapped QK^T)
  const int q0 = wid * 32;
  const unsigned short* qsrc = Qb + ((size_t)(s*R_ + q0 + lr)) * 256 + h*32;
  s16x8 bq0 = *(const s16x8*)(qsrc + 8*hi);
  s16x8 bq1 = *(const s16x8*)(qsrc + 16 + 8*hi);

  f32x16 of;
#pragma unroll
  for (int r = 0; r < 16; r++) of[r] = 0.f;
  float mrun = -1e30f, lsum = 0.f;

  __syncthreads();

  for (int kt = 0; kt < 12; kt++) {
    s16x8 ak0 = *(const s16x8*)&Kl[kt*32 + lr][8*hi];
    s16x8 ak1 = *(const s16x8*)&Kl[kt*32 + lr][16 + 8*hi];
    s16x8 bv0 = *(const s16x8*)&VT[lr][kt*32 + 8*hi];
    s16x8 bv1 = *(const s16x8*)&VT[lr][kt*32 + 16 + 8*hi];

    f32x16 p;
#pragma unroll
    for (int r = 0; r < 16; r++) p[r] = mb[kt*32 + (r & 3) + 8*(r >> 2) + 4*hi];
    __builtin_amdgcn_s_setprio(1);
    p = MFMA32(ak0, bq0, p);
    p = MFMA32(ak1, bq1, p);
    __builtin_amdgcn_s_setprio(0);

    float m01 = fmaxf(fmaxf(p[0], p[1]), fmaxf(p[2], p[3]));
    float m23 = fmaxf(fmaxf(p[4], p[5]), fmaxf(p[6], p[7]));
    float m45 = fmaxf(fmaxf(p[8], p[9]), fmaxf(p[10], p[11]));
    float m67 = fmaxf(fmaxf(p[12], p[13]), fmaxf(p[14], p[15]));
    float pm = fmaxf(fmaxf(m01, m23), fmaxf(m45, m67));
    pm = fmaxf(pm, __shfl_xor(pm, 32));
    if (!__all(pm <= mrun + 11.54f)) {          // defer-max (log2 units)
      float nm = fmaxf(mrun, pm);
      float al = __builtin_amdgcn_exp2f(mrun - nm);
      mrun = nm;
      lsum *= al;
      if (hi == 0) sAl[wid][lr] = al;
#pragma unroll
      for (int r = 0; r < 16; r++)
        of[r] *= sAl[wid][(r & 3) + 8*(r >> 2) + 4*hi];
    }
    float ls = 0.f;
#pragma unroll
    for (int r = 0; r < 16; r++) {
      p[r] = __builtin_amdgcn_exp2f(p[r] - mrun);
      ls += p[r];
    }
    lsum += ls;

    // P -> bf16 via v_cvt_pk (RNE), halves swapped -> PV A-fragments
    uint32_t w0, w1, w2, w3, w4, w5, w6, w7;
    asm("v_cvt_pk_bf16_f32 %0, %1, %2" : "=v"(w0) : "v"(p[0]),  "v"(p[1]));
    asm("v_cvt_pk_bf16_f32 %0, %1, %2" : "=v"(w1) : "v"(p[2]),  "v"(p[3]));
    asm("v_cvt_pk_bf16_f32 %0, %1, %2" : "=v"(w2) : "v"(p[4]),  "v"(p[5]));
    asm("v_cvt_pk_bf16_f32 %0, %1, %2" : "=v"(w3) : "v"(p[6]),  "v"(p[7]));
    asm("v_cvt_pk_bf16_f32 %0, %1, %2" : "=v"(w4) : "v"(p[8]),  "v"(p[9]));
    asm("v_cvt_pk_bf16_f32 %0, %1, %2" : "=v"(w5) : "v"(p[10]), "v"(p[11]));
    asm("v_cvt_pk_bf16_f32 %0, %1, %2" : "=v"(w6) : "v"(p[12]), "v"(p[13]));
    asm("v_cvt_pk_bf16_f32 %0, %1, %2" : "=v"(w7) : "v"(p[14]), "v"(p[15]));
    asm volatile("v_permlane32_swap_b32 %0, %1" : "+v"(w0), "+v"(w2));
    asm volatile("v_permlane32_swap_b32 %0, %1" : "+v"(w1), "+v"(w3));
    asm volatile("v_permlane32_swap_b32 %0, %1" : "+v"(w4), "+v"(w6));
    asm volatile("v_permlane32_swap_b32 %0, %1" : "+v"(w5), "+v"(w7));
    i32x4 pa0i = {(int)w0, (int)w1, (int)w2, (int)w3};
    i32x4 pa1i = {(int)w4, (int)w5, (int)w6, (int)w7};
    __builtin_amdgcn_s_setprio(1);
    of = MFMA32(__builtin_bit_cast(s16x8, pa0i), bv0, of);
    of = MFMA32(__builtin_bit_cast(s16x8, pa1i), bv1, of);
    __builtin_amdgcn_s_setprio(0);
  }

  float lt = lsum + __shfl_xor(lsum, 32);
  float inv = 1.0f / lt;
  if (hi == 0) sAl[wid][lr] = inv;
#pragma unroll
  for (int r = 0; r < 16; r++) {
    int crow = (r & 3) + 8*(r >> 2) + 4*hi;
    float iv = sAl[wid][crow];
    size_t off = ((size_t)(s*R_ + q0 + crow)) * 256 + h*32 + lr;
    float gv = bf2f(Gb[off]);
    Ob[off] = f2bf(of[r] * iv * gv);
  }
}

// ---------------------------------------------------------------------------
// Kernel 4: output GEMM. 64x128 tile, same structure as proj. Out fp32 + bo.
// ---------------------------------------------------------------------------
__global__ __launch_bounds__(256, 5) void out_gemm(const unsigned short* __restrict__ Ob,
    const unsigned short* __restrict__ WT, const float* __restrict__ bo,
    float* __restrict__ Out) {
  __shared__ __align__(16) unsigned short As[64 * 32];
  __shared__ __align__(16) unsigned short Bs[128 * 32];
  const unsigned short* Wt = WT + 4 * 65536;
  const int tid = threadIdx.x;
  const int bn = blockIdx.x * 128;
  const int bm = blockIdx.y * 64;
  const int lane = tid & 63, wid = tid >> 6;
  const int wr = (wid >> 1) * 32, wc = (wid & 1) * 64;
  const int lr = lane & 31, hi = lane >> 5;
  const int srow = lane >> 2, scol = (lane & 3) * 8;

  f32x16 acc0, acc1;
#pragma unroll
  for (int r = 0; r < 16; r++) { acc0[r] = 0.f; acc1[r] = 0.f; }

  for (int k0 = 0; k0 < 256; k0 += 32) {
    gload16(Ob + (size_t)(bm + wid*16 + srow) * 256 + k0 + scol, &As[wid * 512]);
#pragma unroll
    for (int i = 0; i < 2; i++) {
      const int rb = wid * 32 + i * 16;
      gload16(Wt + (size_t)(bn + rb + srow) * 256 + k0 + scol, &Bs[rb * 32]);
    }
    asm volatile("s_waitcnt vmcnt(0)" ::: "memory");
    __syncthreads();
#pragma unroll
    for (int kh = 0; kh < 2; kh++) {
      s16x8 a0 = *(const s16x8*)&As[(wr + lr) * 32      + kh*16 + 8*hi];
      s16x8 b0 = *(const s16x8*)&Bs[(wc + lr) * 32      + kh*16 + 8*hi];
      s16x8 b1 = *(const s16x8*)&Bs[(wc + 32 + lr) * 32 + kh*16 + 8*hi];
      acc0 = MFMA32(a0, b0, acc0);
      acc1 = MFMA32(a0, b1, acc1);
    }
    __syncthreads();
  }

#pragma unroll
  for (int ns = 0; ns < 2; ns++) {
    const f32x16& a = ns ? acc1 : acc0;
    int colg = bn + wc + ns*32 + lr;
    float bov = bo[colg];
#pragma unroll
    for (int r = 0; r < 16; r++) {
      int row = bm + wr + (r & 3) + 8*(r >> 2) + 4*hi;
      Out[(size_t)row * 256 + colg] = a[r] + bov;
    }
  }
}

// ---------------------------------------------------------------------------
// Host launcher
// ---------------------------------------------------------------------------
extern "C" void kernel_launch(void* const* d_in, const int* in_sizes, int n_in,
                              void* d_out, int out_size, void* d_ws, size_t ws_size,
                              hipStream_t stream) {
  const float* m    = (const float*)d_in[0];
  const float* mask = (const float*)d_in[1];
  const float* ln_w = (const float*)d_in[2];
  const float* ln_b = (const float*)d_in[3];
  const float* wq   = (const float*)d_in[4];
  const float* wk   = (const float*)d_in[5];
  const float* wv   = (const float*)d_in[6];
  const float* wg   = (const float*)d_in[7];
  const float* bg   = (const float*)d_in[8];
  const float* wo   = (const float*)d_in[9];
  const float* bo   = (const float*)d_in[10];
  float* out = (float*)d_out;

  unsigned short* ws = (unsigned short*)d_ws;
  const size_t SZ = (size_t)M_ * 256;
  unsigned short* xbf = ws;
  unsigned short* qb  = ws + 1 * SZ;
  unsigned short* kb  = ws + 2 * SZ;
  unsigned short* vb  = ws + 3 * SZ;
  unsigned short* gb  = ws + 4 * SZ;
  unsigned short* ob  = ws + 5 * SZ;
  unsigned short* WT  = ws + 6 * SZ;

  prep_w<<<80, 256, 0, stream>>>(wq, wk, wv, wg, wo, WT);
  ln_kernel<<<M_ / 4, 256, 0, stream>>>(m, ln_w, ln_b, xbf);
  proj_gemm<<<dim3(8, M_ / 64), 256, 0, stream>>>(xbf, WT, bg, qb, kb, vb, gb);
  attn_kernel<<<dim3(H_, S_), 768, 0, stream>>>(qb, kb, vb, gb, mask, ob);
  out_gemm<<<dim3(2, M_ / 64), 256, 0, stream>>>(ob, WT, bo, out);
}